// Round 1
// baseline (1273.546 us; speedup 1.0000x reference)
//
#include <hip/hip_runtime.h>

// ---------------------------------------------------------------------------
// AdderNet 6-layer stack on MI355X.
// out[n,o,i,j] = -sum_k |patch - w|  (no MFMA possible -> VALU sub+abs-add)
// BN(batch stats)+ReLU6 folded into the NEXT conv's staging load.
// ---------------------------------------------------------------------------

// Conv kernel: block = 256 threads, tile = 64 out-channels x 64 pixels,
// 4x4 micro-tile per thread. K staged in LDS chunks of KC, layout [k][col]
// so inner loop reads are 2x ds_read_b128 per 32 VALU ops.
template <int KC, bool IS3x3>
__global__ __launch_bounds__(256, 4)
void adder_conv(const float* __restrict__ x, const float* __restrict__ wT,
                const float2* __restrict__ ab, float* __restrict__ out,
                int Cin, int H, int W, int Wo, int Cout,
                int stride, int pad, int chunks, int P, int PI)
{
    __shared__ float xs[KC][64];
    __shared__ float ws[KC][64];
    const int t  = threadIdx.x;
    const int tx = t & 15, ty = t >> 4;
    const int ptile = blockIdx.x * 64, otile = blockIdx.y * 64;
    const int pp = t & 63, rg = t >> 6;   // staging: column + row-group

    // decode this thread's staging pixel once (fixed across all chunks)
    const int p_st = ptile + pp;
    const bool pv = p_st < P;
    int n_st = 0, q = 0;
    if (pv) { n_st = p_st / PI; q = p_st - n_st * PI; }
    const int oh = q / Wo, ow = q - oh * Wo;
    const int ih0 = oh * stride - pad, iw0 = ow * stride - pad;
    const float* xb = x + (size_t)n_st * Cin * H * W;
    const bool hasBN = (ab != nullptr);

    float acc[4][4] = {};

    for (int ch = blockIdx.z; ch < chunks; ch += gridDim.z) {
        const int k0 = ch * KC;
        // ---- stage activations (apply BN+ReLU6 of previous layer on load;
        //      padding positions stay literal 0, per reference semantics)
#pragma unroll
        for (int j = 0; j < KC / 4; ++j) {
            const int kk = j * 4 + rg;
            const int k  = k0 + kk;
            float v = 0.f;
            if (pv) {
                int c, ih, iw;
                if (IS3x3) {
                    c = k / 9; const int r = k - c * 9;
                    const int kh = r / 3, kw = r - kh * 3;
                    ih = ih0 + kh; iw = iw0 + kw;
                } else { c = k; ih = ih0; iw = iw0; }
                if (ih >= 0 && ih < H && iw >= 0 && iw < W) {
                    float raw = xb[(c * H + ih) * W + iw];
                    if (hasBN) {
                        const float2 s = ab[c];
                        raw = fminf(fmaxf(fmaf(s.x, raw, s.y), 0.f), 6.f);
                    }
                    v = raw;
                }
            }
            xs[kk][pp] = v;
        }
        // ---- stage weights (pre-transposed [K][Cout] -> coalesced)
#pragma unroll
        for (int j = 0; j < KC / 4; ++j) {
            const int kk = j * 4 + rg;
            ws[kk][pp] = wT[(size_t)(k0 + kk) * Cout + otile + pp];
        }
        __syncthreads();
        // ---- inner: 2 ds_read_b128 + 32 VALU per k
#pragma unroll 4
        for (int kk = 0; kk < KC; ++kk) {
            const float4 xv = *(const float4*)&xs[kk][tx * 4];
            const float4 wv = *(const float4*)&ws[kk][ty * 4];
            const float xr[4] = {xv.x, xv.y, xv.z, xv.w};
            const float wr[4] = {wv.x, wv.y, wv.z, wv.w};
#pragma unroll
            for (int i = 0; i < 4; ++i)
#pragma unroll
                for (int jj = 0; jj < 4; ++jj)
                    acc[i][jj] += fabsf(xr[i] - wr[jj]);
        }
        __syncthreads();
    }

    // ---- write partials (split-K -> atomic accumulate into zeroed buffer)
#pragma unroll
    for (int i = 0; i < 4; ++i) {
        const int p = ptile + tx * 4 + i;
        if (p >= P) continue;
        const int n = p / PI, qq = p - n * PI;
#pragma unroll
        for (int jj = 0; jj < 4; ++jj) {
            const int o = otile + ty * 4 + jj;
            unsafeAtomicAdd(&out[((size_t)n * Cout + o) * PI + qq], -acc[i][jj]);
        }
    }
}

// per-channel sum / sumsq in double (one block per channel, plain stores)
__global__ void stats_kernel(const float* __restrict__ y, double* __restrict__ st,
                             int C, int N, int PI)
{
    const int c = blockIdx.x, t = threadIdx.x;
    double s = 0.0, s2 = 0.0;
    for (int n = 0; n < N; ++n) {
        const float* row = y + ((size_t)n * C + c) * PI;
        for (int qq = t; qq < PI; qq += 256) {
            const float v = row[qq];
            s += v; s2 += (double)v * v;
        }
    }
    __shared__ double sh[256], sh2[256];
    sh[t] = s; sh2[t] = s2; __syncthreads();
    for (int off = 128; off > 0; off >>= 1) {
        if (t < off) { sh[t] += sh[t + off]; sh2[t] += sh2[t + off]; }
        __syncthreads();
    }
    if (t == 0) { st[2 * c] = sh[0]; st[2 * c + 1] = sh2[0]; }
}

// per-channel affine fold: y = a*x + b  with a = g*rsqrt(var+eps), b = beta - mean*a
__global__ void ab_kernel(const double* __restrict__ st, const float* __restrict__ gamma,
                          const float* __restrict__ beta, float2* __restrict__ ab,
                          int C, double invCount)
{
    const int c = blockIdx.x * blockDim.x + threadIdx.x;
    if (c < C) {
        const double mean = st[2 * c] * invCount;
        const double var  = st[2 * c + 1] * invCount - mean * mean;
        const float a = gamma[c] * rsqrtf((float)var + 1e-5f);
        const float b = beta[c] - (float)mean * a;
        ab[c] = make_float2(a, b);
    }
}

// final BN+ReLU6 -> d_out
__global__ void apply_kernel(const float* __restrict__ y, const float2* __restrict__ ab,
                             float* __restrict__ out, int total, int C, int PI)
{
    const int i = blockIdx.x * 256 + threadIdx.x;
    if (i < total) {
        const int c = (i / PI) % C;
        const float2 s = ab[c];
        out[i] = fminf(fmaxf(fmaf(s.x, y[i], s.y), 0.f), 6.f);
    }
}

// w [Cout][K] -> wT [K][Cout]
__global__ void transpose_w(const float* __restrict__ w, float* __restrict__ wT,
                            int Cout, int K)
{
    const int i = blockIdx.x * 256 + threadIdx.x;
    if (i < Cout * K) {
        const int k = i / Cout, o = i - k * Cout;
        wT[i] = w[(size_t)o * K + k];
    }
}

extern "C" void kernel_launch(void* const* d_in, const int* in_sizes, int n_in,
                              void* d_out, int out_size, void* d_ws, size_t ws_size,
                              hipStream_t stream)
{
    const float* x = (const float*)d_in[0];
    const float *w[6], *g[6], *bt[6];
    for (int i = 0; i < 6; ++i) {
        w[i]  = (const float*)d_in[1 + 3 * i];
        g[i]  = (const float*)d_in[2 + 3 * i];
        bt[i] = (const float*)d_in[3 + 3 * i];
    }

    char* ws = (char*)d_ws;
    float* bufA = (float*)ws;                                   // 5,914,624 f
    float* bufB = (float*)(ws + 23658496);                      // 2,957,312 f
    size_t off = 23658496 + 11829248;
    const int wElems[6] = {256 * 512, 512 * 2304, 128 * 512,
                           256 * 1152, 128 * 256, 256 * 1152};
    float* wT[6];
    for (int i = 0; i < 6; ++i) { wT[i] = (float*)(ws + off); off += (size_t)wElems[i] * 4; }
    double* st = (double*)(ws + off); off += 3072 * 8;
    float2* ab = (float2*)(ws + off);
    // stats offsets (doubles) / ab offsets (float2) per layer
    const int stOff[6] = {0, 512, 1536, 1792, 2304, 2560};
    const int abOff[6] = {0, 256, 768, 896, 1152, 1280};

    const dim3 blk(256);

    // weight transposes
    const int wCout[6] = {256, 512, 128, 256, 128, 256};
    const int wK[6]    = {512, 2304, 512, 1152, 256, 1152};
    for (int i = 0; i < 6; ++i)
        transpose_w<<<(wElems[i] + 255) / 256, blk, 0, stream>>>(w[i], wT[i], wCout[i], wK[i]);

    // ---- L1: 1x1, 512->256, 38x38, P=23104
    hipMemsetAsync(bufA, 0, (size_t)23104 * 256 * 4, stream);
    adder_conv<64, false><<<dim3(361, 4, 1), blk, 0, stream>>>(
        x, wT[0], nullptr, bufA, 512, 38, 38, 38, 256, 1, 0, 8, 23104, 1444);
    stats_kernel<<<256, blk, 0, stream>>>(bufA, st + stOff[0], 256, 16, 1444);
    ab_kernel<<<1, blk, 0, stream>>>(st + stOff[0], g[0], bt[0], ab + abOff[0], 256, 1.0 / 23104);

    // ---- L2: 3x3 s2 p1, 256->512, 38->19, P=5776, K=2304
    hipMemsetAsync(bufB, 0, (size_t)5776 * 512 * 4, stream);
    adder_conv<72, true><<<dim3(91, 8, 2), blk, 0, stream>>>(
        bufA, wT[1], ab + abOff[0], bufB, 256, 38, 38, 19, 512, 2, 1, 32, 5776, 361);
    stats_kernel<<<512, blk, 0, stream>>>(bufB, st + stOff[1], 512, 16, 361);
    ab_kernel<<<2, blk, 0, stream>>>(st + stOff[1], g[1], bt[1], ab + abOff[1], 512, 1.0 / 5776);

    // ---- L3: 1x1, 512->128, 19x19, P=5776, K=512
    hipMemsetAsync(bufA, 0, (size_t)5776 * 128 * 4, stream);
    adder_conv<64, false><<<dim3(91, 2, 4), blk, 0, stream>>>(
        bufB, wT[2], ab + abOff[1], bufA, 512, 19, 19, 19, 128, 1, 0, 8, 5776, 361);
    stats_kernel<<<128, blk, 0, stream>>>(bufA, st + stOff[2], 128, 16, 361);
    ab_kernel<<<1, blk, 0, stream>>>(st + stOff[2], g[2], bt[2], ab + abOff[2], 128, 1.0 / 5776);

    // ---- L4: 3x3 s2 p1, 128->256, 19->10, P=1600, K=1152
    hipMemsetAsync(bufB, 0, (size_t)1600 * 256 * 4, stream);
    adder_conv<72, true><<<dim3(25, 4, 8), blk, 0, stream>>>(
        bufA, wT[3], ab + abOff[2], bufB, 128, 19, 19, 10, 256, 2, 1, 16, 1600, 100);
    stats_kernel<<<256, blk, 0, stream>>>(bufB, st + stOff[3], 256, 16, 100);
    ab_kernel<<<1, blk, 0, stream>>>(st + stOff[3], g[3], bt[3], ab + abOff[3], 256, 1.0 / 1600);

    // ---- L5: 1x1, 256->128, 10x10, P=1600, K=256
    hipMemsetAsync(bufA, 0, (size_t)1600 * 128 * 4, stream);
    adder_conv<64, false><<<dim3(25, 2, 4), blk, 0, stream>>>(
        bufB, wT[4], ab + abOff[3], bufA, 256, 10, 10, 10, 128, 1, 0, 4, 1600, 100);
    stats_kernel<<<128, blk, 0, stream>>>(bufA, st + stOff[4], 128, 16, 100);
    ab_kernel<<<1, blk, 0, stream>>>(st + stOff[4], g[4], bt[4], ab + abOff[4], 128, 1.0 / 1600);

    // ---- L6: 3x3 s2 p0, 128->256, 10->4, P=256, K=1152
    hipMemsetAsync(bufB, 0, (size_t)256 * 256 * 4, stream);
    adder_conv<72, true><<<dim3(4, 4, 16), blk, 0, stream>>>(
        bufA, wT[5], ab + abOff[4], bufB, 128, 10, 10, 4, 256, 2, 0, 16, 256, 16);
    stats_kernel<<<256, blk, 0, stream>>>(bufB, st + stOff[5], 256, 16, 16);
    ab_kernel<<<1, blk, 0, stream>>>(st + stOff[5], g[5], bt[5], ab + abOff[5], 256, 1.0 / 256);

    // ---- final BN+ReLU6 -> out
    apply_kernel<<<(65536 + 255) / 256, blk, 0, stream>>>(bufB, ab + abOff[5], (float*)d_out,
                                                          65536, 256, 16);
}